// Round 5
// baseline (252.212 us; speedup 1.0000x reference)
//
#include <hip/hip_runtime.h>
#include <hip/hip_bf16.h>

typedef unsigned short u16;
typedef unsigned char u8;
typedef float f32x4 __attribute__((ext_vector_type(4)));
typedef int int4v __attribute__((ext_vector_type(4)));
typedef int int8v __attribute__((ext_vector_type(8)));

#define B_ROWS 8192
#define D_DIM  1024
#define FP8_SCALE 16.0f          // store x*16 in e4m3; acc = 256 * s_true
#define ACC_UNSCALE (1.0f/256.0f)

// ---------------------------------------------------------------------------
// Workspace layout (bytes):
//   [0,      32768)   ppq[8192]   per-row MSE(q) partial
//   [32768,  65536)   ppp[8192]   per-row MSE(p) partial
//   [65536,  98304)   ppd[8192]   per-row diag cosine (exact fp32)
//   [98304,  98816)   bpart[32][4] per-reduce-block partials
//   [131072, +2MiB)   gpart[64][8192]  per-bn row exp-sum partials
//   [+2MiB,  +8MiB)   qn fp8 [8192][1024]   (x16 pre-scaled e4m3)
//   [...,    +8MiB)   pn fp8 [8192][1024]
// No pre-zeroing required: every cell is written before it is read.
// ---------------------------------------------------------------------------

// ---------------------------------------------------------------------------
// Kernel 1: one WAVE per row — no barriers, no LDS, pure butterfly reduce.
// ---------------------------------------------------------------------------
__global__ void __launch_bounds__(256) prep_kernel(
    const float* __restrict__ sq, const float* __restrict__ sp,
    const float* __restrict__ tq, const float* __restrict__ tp,
    int* __restrict__ qn, int* __restrict__ pn,
    float* __restrict__ ppq, float* __restrict__ ppp, float* __restrict__ ppd)
{
    const int wave = threadIdx.x >> 6;
    const int l    = threadIdx.x & 63;
    const int r    = blockIdx.x * 4 + wave;
    const size_t rb4 = (size_t)r * (D_DIM / 4);

    const float4* Q4 = (const float4*)sq + rb4;
    const float4* P4 = (const float4*)sp + rb4;
    const float4* A4 = (const float4*)tq + rb4;
    const float4* B4 = (const float4*)tp + rb4;

    float4 qv[4], pv[4];
    float sq2 = 0.f, sp2 = 0.f, dq = 0.f, dp = 0.f, qp = 0.f;
    #pragma unroll
    for (int j = 0; j < 4; ++j) {
        const int idx = j * 64 + l;
        float4 q = Q4[idx], p = P4[idx], a = A4[idx], b = B4[idx];
        qv[j] = q; pv[j] = p;
        sq2 += q.x*q.x + q.y*q.y + q.z*q.z + q.w*q.w;
        sp2 += p.x*p.x + p.y*p.y + p.z*p.z + p.w*p.w;
        float dx = q.x-a.x, dy = q.y-a.y, dz = q.z-a.z, dw = q.w-a.w;
        dq += dx*dx + dy*dy + dz*dz + dw*dw;
        dx = p.x-b.x; dy = p.y-b.y; dz = p.z-b.z; dw = p.w-b.w;
        dp += dx*dx + dy*dy + dz*dz + dw*dw;
        qp += q.x*p.x + q.y*p.y + q.z*p.z + q.w*p.w;
    }

    #pragma unroll
    for (int m = 1; m <= 32; m <<= 1) {
        sq2 += __shfl_xor(sq2, m);
        sp2 += __shfl_xor(sp2, m);
        dq  += __shfl_xor(dq, m);
        dp  += __shfl_xor(dp, m);
        qp  += __shfl_xor(qp, m);
    }

    const float rq = 1.0f / fmaxf(sqrtf(sq2), 1e-8f);
    const float rp = 1.0f / fmaxf(sqrtf(sp2), 1e-8f);

    if (l == 0) {
        ppq[r] = dq;
        ppp[r] = dp;
        ppd[r] = qp * rq * rp;   // exact fp32 diagonal cosine
    }

    const float fq = rq * FP8_SCALE;
    const float fp = rp * FP8_SCALE;
    int* qrow = qn + (size_t)r * (D_DIM / 4);
    int* prow = pn + (size_t)r * (D_DIM / 4);
    #pragma unroll
    for (int j = 0; j < 4; ++j) {
        const int idx = j * 64 + l;
        int pk = __builtin_amdgcn_cvt_pk_fp8_f32(qv[j].x * fq, qv[j].y * fq, 0, false);
        pk     = __builtin_amdgcn_cvt_pk_fp8_f32(qv[j].z * fq, qv[j].w * fq, pk, true);
        qrow[idx] = pk;
        pk = __builtin_amdgcn_cvt_pk_fp8_f32(pv[j].x * fp, pv[j].y * fp, 0, false);
        pk = __builtin_amdgcn_cvt_pk_fp8_f32(pv[j].z * fp, pv[j].w * fp, pk, true);
        prow[idx] = pk;
    }
}

// ---------------------------------------------------------------------------
// Kernel 2: S = Qn @ Pn^T via MX-scaled fp8 MFMA 16x16x128 (unit scales).
// Block = 128 threads (2 waves), tile 128x128, BK=128.
// Wave w computes rows [64w, 64w+64) x ALL 128 cols (wave tile 64x128):
// cuts per-staged-byte LDS reads from 2 waves to 1.5 avg (A exclusive,
// B shared by 2) -> 0.75x LDS-pipe traffic vs 2x2 wave grid.
// acc = 4x8 f32x4 = 128 VGPRs; bf loaded inside ni-loop to bound pressure.
// ---------------------------------------------------------------------------
__global__ void __launch_bounds__(128, 2) gemm_rowsum_kernel(
    const u8* __restrict__ Q, const u8* __restrict__ P,
    float* __restrict__ gpart)
{
    __shared__ u8 smA[128 * 128];   // 16 KiB, row stride 128 B
    __shared__ u8 smB[128 * 128];

    const int tid  = threadIdx.x;
    const int wave = tid >> 6;      // 0..1
    const int lane = tid & 63;
    const int bm = blockIdx.y;
    const int bn = blockIdx.x;

    // staging: each global_load_lds covers 8 rows x 128 B (1 KiB)
    const int lrow   = lane >> 3;               // row within 8-row chunk
    const int gchunk = (lane & 7) ^ lrow;       // XOR swizzle of 16B chunks
    const u8* Ag = Q + ((size_t)bm * 128) * D_DIM + gchunk * 16;
    const u8* Bg = P + ((size_t)bn * 128) * D_DIM + gchunk * 16;

    const int quad  = lane >> 4;
    const int rw    = lane & 15;
    const int r7    = lane & 7;                 // == row&7 for fragment rows
    const int arow0 = wave * 64;                // wave's row strip in tile

    // fragment = global k [32*quad, 32*quad+32) of its row:
    // 16B chunks 2q and 2q+1, stored at positions (2q)^r7 and (2q+1)^r7
    const int off_lo = ((2 * quad) ^ r7) * 16;
    const int off_hi = ((2 * quad + 1) ^ r7) * 16;

    f32x4 acc[4][8];
    #pragma unroll
    for (int i = 0; i < 4; ++i)
        #pragma unroll
        for (int j = 0; j < 8; ++j)
            acc[i][j] = (f32x4){0.f, 0.f, 0.f, 0.f};

    union Frag { int8v v8; struct { int4v lo, hi; } h; };

    for (int k0 = 0; k0 < D_DIM; k0 += 128) {
        // stage 128 rows of A and B; each wave does 8+8 insts of 8 rows
        #pragma unroll
        for (int i = 0; i < 8; ++i) {
            const int r0 = wave * 64 + i * 8;
            __builtin_amdgcn_global_load_lds(
                (const __attribute__((address_space(1))) void*)(Ag + (size_t)(r0 + lrow) * D_DIM + k0),
                (__attribute__((address_space(3))) void*)(smA + r0 * 128), 16, 0, 0);
            __builtin_amdgcn_global_load_lds(
                (const __attribute__((address_space(1))) void*)(Bg + (size_t)(r0 + lrow) * D_DIM + k0),
                (__attribute__((address_space(3))) void*)(smB + r0 * 128), 16, 0, 0);
        }
        __syncthreads();

        Frag af[4];
        #pragma unroll
        for (int mi = 0; mi < 4; ++mi) {
            const u8* row = smA + (arow0 + mi * 16 + rw) * 128;
            af[mi].h.lo = *(const int4v*)(row + off_lo);
            af[mi].h.hi = *(const int4v*)(row + off_hi);
        }
        #pragma unroll
        for (int ni = 0; ni < 8; ++ni) {
            Frag bf;
            const u8* row = smB + (ni * 16 + rw) * 128;
            bf.h.lo = *(const int4v*)(row + off_lo);
            bf.h.hi = *(const int4v*)(row + off_hi);
            #pragma unroll
            for (int mi = 0; mi < 4; ++mi)
                acc[mi][ni] = __builtin_amdgcn_mfma_scale_f32_16x16x128_f8f6f4(
                    af[mi].v8, bf.v8, acc[mi][ni],
                    0, 0,                       // cbsz=fp8, blgp=fp8
                    0, 0x7f7f7f7f,              // scale A = 1.0
                    0, 0x7f7f7f7f);             // scale B = 1.0
        }
        __syncthreads();
    }

    // epilogue: per-row sum of exp over this wave's 128 columns.
    // C/D layout (shape-determined): col = lane&15, row = quad*4 + reg
    float esum[4][4];
    #pragma unroll
    for (int mi = 0; mi < 4; ++mi)
        #pragma unroll
        for (int r = 0; r < 4; ++r) {
            float s = 0.f;
            #pragma unroll
            for (int ni = 0; ni < 8; ++ni)
                s += __expf(acc[mi][ni][r] * ACC_UNSCALE);
            esum[mi][r] = s;
        }
    #pragma unroll
    for (int m = 1; m <= 8; m <<= 1)
        #pragma unroll
        for (int mi = 0; mi < 4; ++mi)
            #pragma unroll
            for (int r = 0; r < 4; ++r)
                esum[mi][r] += __shfl_xor(esum[mi][r], m);

    // rows are wave-exclusive within the block -> slice index is just bn
    if (rw == 0) {
        float* dst = gpart + (size_t)bn * B_ROWS + bm * 128 + arow0;
        #pragma unroll
        for (int mi = 0; mi < 4; ++mi)
            #pragma unroll
            for (int r = 0; r < 4; ++r)
                dst[mi * 16 + quad * 4 + r] = esum[mi][r];
    }
}

// ---------------------------------------------------------------------------
// Kernel 3: per-row sum of 64 gpart slices -> log; fold in the three
// pp-array reductions; one float4 partial per block.
// ---------------------------------------------------------------------------
__global__ void __launch_bounds__(256) reduce_kernel(
    const float* __restrict__ gpart,
    const float* __restrict__ ppq, const float* __restrict__ ppp,
    const float* __restrict__ ppd, float4* __restrict__ bpart)
{
    const int t = threadIdx.x;
    const int r = blockIdx.x * 256 + t;
    float s = 0.f;
    #pragma unroll 8
    for (int j = 0; j < 64; ++j) s += gpart[(size_t)j * B_ROWS + r];
    float ls = logf(s);
    float v2 = ppq[r], v3 = ppp[r], v4 = ppd[r];
    #pragma unroll
    for (int m = 1; m <= 32; m <<= 1) {
        ls += __shfl_xor(ls, m);
        v2 += __shfl_xor(v2, m);
        v3 += __shfl_xor(v3, m);
        v4 += __shfl_xor(v4, m);
    }
    __shared__ float red[4][4];
    if ((t & 63) == 0) {
        red[t >> 6][0] = ls; red[t >> 6][1] = v2;
        red[t >> 6][2] = v3; red[t >> 6][3] = v4;
    }
    __syncthreads();
    if (t == 0) {
        float4 o;
        o.x = red[0][0] + red[1][0] + red[2][0] + red[3][0];
        o.y = red[0][1] + red[1][1] + red[2][1] + red[3][1];
        o.z = red[0][2] + red[1][2] + red[2][2] + red[3][2];
        o.w = red[0][3] + red[1][3] + red[2][3] + red[3][3];
        bpart[blockIdx.x] = o;
    }
}

// ---------------------------------------------------------------------------
// Kernel 4: final scalar combine (1 wave, 32 float4 partials)
// ---------------------------------------------------------------------------
__global__ void __launch_bounds__(64) finalize_kernel(
    const float4* __restrict__ bpart, float* __restrict__ out)
{
    const int t = threadIdx.x;
    float4 v = (t < 32) ? bpart[t] : (float4){0.f, 0.f, 0.f, 0.f};
    #pragma unroll
    for (int m = 1; m <= 16; m <<= 1) {
        v.x += __shfl_xor(v.x, m);
        v.y += __shfl_xor(v.y, m);
        v.z += __shfl_xor(v.z, m);
        v.w += __shfl_xor(v.w, m);
    }
    if (t == 0) {
        const float inv_bd = 1.0f / ((float)B_ROWS * (float)D_DIM);
        float distill   = 0.5f * (v.y + v.z) * inv_bd;
        float retrieval = (v.x - v.w) / (float)B_ROWS;
        out[0] = 0.5f * distill + 0.5f * retrieval;
    }
}

extern "C" void kernel_launch(void* const* d_in, const int* in_sizes, int n_in,
                              void* d_out, int out_size, void* d_ws, size_t ws_size,
                              hipStream_t stream) {
    const float* sq = (const float*)d_in[0];
    const float* sp = (const float*)d_in[1];
    const float* tq = (const float*)d_in[2];
    const float* tp = (const float*)d_in[3];

    char* ws = (char*)d_ws;
    float*  ppq   = (float*)(ws);
    float*  ppp   = (float*)(ws + 32768);
    float*  ppd   = (float*)(ws + 65536);
    float4* bpart = (float4*)(ws + 98304);
    float*  gpart = (float*)(ws + 131072);                        // 2 MiB
    int*    qn    = (int*)(ws + 131072 + (size_t)64 * B_ROWS * 4);
    int*    pn    = (int*)((char*)qn + (size_t)B_ROWS * D_DIM);

    prep_kernel<<<B_ROWS / 4, 256, 0, stream>>>(sq, sp, tq, tp, qn, pn, ppq, ppp, ppd);
    gemm_rowsum_kernel<<<dim3(64, 64), 128, 0, stream>>>((const u8*)qn, (const u8*)pn, gpart);
    reduce_kernel<<<32, 256, 0, stream>>>(gpart, ppq, ppp, ppd, bpart);
    finalize_kernel<<<1, 64, 0, stream>>>(bpart, (float*)d_out);
}